// Round 1
// baseline (48.622 us; speedup 1.0000x reference)
//
#include <hip/hip_runtime.h>

// LRP m-rule backward through AdaptiveAvgPool2d (56x56 -> 7x7, window 8x8, k=64).
//
// With theta = 180deg: COS_T = -1.0 exactly, SIN_T ~ 1.2246e-16.
// Algebra: nx*norm_x == x exactly, so x_head = -x + O(1e-16), x_diff = 2x + dust,
// wx_diff = x/32 + dust, sum(wx_diff) = Sx/32 + dust, and
//   out_i = (x_i/32) / (Sx/32 + eps) * r = x_i * r / (Sx + 32*eps)
// Dust terms are ~1e-16 absolute in the window sum; worst-case denominator over
// all 401408 windows is ~8e-7, so dropping them perturbs outputs by ~1e-5
// absolute (threshold is 783). Window sum Sx computed in fp64 so the
// near-cancelling denominator matches an fp64 reference essentially exactly.
//
// Layout: one wave = 2 windows. Lanes 0-31 -> window A, lanes 32-63 -> window B.
// Lane (m = lane&31) loads float2 at (row = m>>3? no: m>>2, col pair (m&3)*2):
// 8 rows x 4 lanes x float2 = 64 elements. Shuffle-xor masks 1..16 stay inside
// each 32-lane half, giving each half its own window sum.

static constexpr int BC    = 32 * 256;       // 8192 (b,c) images
static constexpr int H     = 56, W = 56;
static constexpr int NWIN  = BC * 7 * 7;     // 401408 windows
static constexpr int NPAIR = NWIN / 2;       // 200704 wave-pairs

__global__ __launch_bounds__(256) void lrp_pool_kernel(
    const float* __restrict__ x,
    const float* __restrict__ r,
    float* __restrict__ out)
{
    const int tid  = threadIdx.x;
    const int lane = tid & 63;
    const int half = lane >> 5;   // which window of this wave's pair
    const int m    = lane & 31;   // lane within the half

    const int pairsPerBlock = 4;  // 4 waves / block
    int wp = blockIdx.x * pairsPerBlock + (tid >> 6);
    const int wpStride = gridDim.x * pairsPerBlock;

    for (; wp < NPAIR; wp += wpStride) {
        const int wid = wp * 2 + half;
        const int bc  = wid / 49;            // magic-mul div by const
        const int rem = wid - bc * 49;
        const int ohi = rem / 7;
        const int owi = rem - ohi * 7;

        const int row = (ohi << 3) + (m >> 2);        // 8 rows, 4 lanes each
        const int col = (owi << 3) + ((m & 3) << 1);  // float2 -> cols c, c+1
        const int off = bc * (H * W) + row * W + col; // 8-byte aligned

        const float2 v  = *reinterpret_cast<const float2*>(x + off);
        const float  rv = r[wid];            // one scalar per window (broadcast)

        // fp64 window sum: per-lane pair, then 5-round butterfly within half
        double s = (double)v.x + (double)v.y;
        s += __shfl_xor(s, 1,  64);
        s += __shfl_xor(s, 2,  64);
        s += __shfl_xor(s, 4,  64);
        s += __shfl_xor(s, 8,  64);
        s += __shfl_xor(s, 16, 64);

        const float coef = (float)((double)rv / (s + 32.0 * 1e-5));

        float2 o;
        o.x = v.x * coef;
        o.y = v.y * coef;
        *reinterpret_cast<float2*>(out + off) = o;
    }
}

extern "C" void kernel_launch(void* const* d_in, const int* in_sizes, int n_in,
                              void* d_out, int out_size, void* d_ws, size_t ws_size,
                              hipStream_t stream) {
    const float* x   = (const float*)d_in[0];
    const float* r   = (const float*)d_in[1];
    float*       out = (float*)d_out;
    // 3136 blocks * 4 pairs/block = 12544 pairs per sweep; 200704/12544 = 16 exact iters
    lrp_pool_kernel<<<3136, 256, 0, stream>>>(x, r, out);
}

// Round 2
// 42.830 us; speedup vs baseline: 1.1352x; 1.1352x over previous
//
#include <hip/hip_runtime.h>

// LRP m-rule backward through AdaptiveAvgPool2d (56x56 -> 7x7, window 8x8, k=64).
//
// theta = 180deg => COS_T = -1.0 exactly, SIN_T ~ 1.2e-16. The whole chain
// collapses to  out_i = x_i * r / (Sx + 32*eps)  with Sx = window sum.
// Sx can nearly cancel (min denom ~8e-7 across 401K windows), so Sx is
// accumulated in fp64; the divide itself is fp32 (relative error 6e-8 on the
// denominator -> ~5e-3 absolute on outputs, irrelevant vs threshold 783).
//
// Layout: one wave = 4 windows (16 lanes each), float4 per lane:
//   j = lane&15: row = j>>1 (8 rows), col-group = (j&1)*4  -> 16 x 4 = 64 elems.
// Butterfly reduce with xor masks 1,2,4,8 stays inside each 16-lane group.
// Static trip count 8, unroll 4 -> batches of independent float4 loads in
// flight to hide HBM latency inside a wave.

static constexpr int BC     = 32 * 256;        // 8192 images
static constexpr int HW     = 56 * 56;         // 3136
static constexpr int NWIN   = BC * 49;         // 401408 windows
static constexpr int NGROUP = NWIN / 4;        // 100352 wave-groups of 4 windows
static constexpr int BLOCKS = 3136;
static constexpr int WAVES  = BLOCKS * 4;      // 12544
static constexpr int NITER  = NGROUP / WAVES;  // 8 (exact)

__global__ __launch_bounds__(256) void lrp_pool_kernel(
    const float* __restrict__ x,
    const float* __restrict__ r,
    float* __restrict__ out)
{
    const int tid  = threadIdx.x;
    const int lane = tid & 63;
    const int win  = lane >> 4;   // window within the wave's group of 4
    const int j    = lane & 15;   // lane within the 16-lane window team

    const int g0 = blockIdx.x * 4 + (tid >> 6);

    #pragma unroll 4
    for (int it = 0; it < NITER; ++it) {
        const int g   = g0 + it * WAVES;
        const int wid = g * 4 + win;
        const int bc  = wid / 49;             // magic-mul div
        const int rem = wid - bc * 49;
        const int ohi = rem / 7;
        const int owi = rem - ohi * 7;

        const int row = (ohi << 3) + (j >> 1);
        const int col = (owi << 3) + ((j & 1) << 2);   // float4: cols c..c+3
        const int off = bc * HW + row * 56 + col;      // 16B aligned

        const float4 v  = *reinterpret_cast<const float4*>(x + off);
        const float  rv = r[wid];  // 16 lanes same addr -> broadcast

        // fp64 window sum: per-lane 4-elem sum, then 4-round butterfly
        double s = ((double)v.x + (double)v.y) + ((double)v.z + (double)v.w);
        s += __shfl_xor(s, 1, 64);
        s += __shfl_xor(s, 2, 64);
        s += __shfl_xor(s, 4, 64);
        s += __shfl_xor(s, 8, 64);

        const float denom = (float)(s + 32.0 * 1e-5);
        const float coef  = rv / denom;

        float4 o;
        o.x = v.x * coef;
        o.y = v.y * coef;
        o.z = v.z * coef;
        o.w = v.w * coef;
        *reinterpret_cast<float4*>(out + off) = o;
    }
}

extern "C" void kernel_launch(void* const* d_in, const int* in_sizes, int n_in,
                              void* d_out, int out_size, void* d_ws, size_t ws_size,
                              hipStream_t stream) {
    const float* x   = (const float*)d_in[0];
    const float* r   = (const float*)d_in[1];
    float*       out = (float*)d_out;
    lrp_pool_kernel<<<BLOCKS, 256, 0, stream>>>(x, r, out);
}

// Round 3
// 40.490 us; speedup vs baseline: 1.2008x; 1.0578x over previous
//
#include <hip/hip_runtime.h>

// LRP m-rule backward through AdaptiveAvgPool2d (56x56 -> 7x7, window 8x8, k=64).
//
// theta = 180deg => COS_T = -1.0 exactly, SIN_T ~ 1.2e-16. The whole chain
// collapses to  out_i = x_i * r / (Sx + 32*eps)  with Sx = window sum.
// Sx can nearly cancel (min denom ~8e-7 across 401K windows), so Sx is
// accumulated in fp64; the divide itself is fp32 (relative error 6e-8 on the
// denominator -> ~5e-3 absolute on outputs, irrelevant vs threshold 783).
//
// Layout: one wave = 4 windows (16 lanes each), float4 per lane:
//   j = lane&15: row = j>>1 (8 rows), col-group = (j&1)*4  -> 16 x 4 = 64 elems.
// Butterfly reduce with xor masks 1,2,4,8 stays inside each 16-lane group.
//
// Grid sizing (round-3 fix): 100352 groups = 2^11*7^2. 1792 blocks * 4 waves
// = 7168 waves -> exactly 14 iterations/wave, and 1792 = 7 blocks/CU exactly
// (28/32 waves resident, VGPR=32 no cap). Single resident pass, no second-pass
// tail (previous 3136-block grid was 1.53x capacity -> ~1.3x slowdown).

static constexpr int BC     = 32 * 256;        // 8192 images
static constexpr int HW     = 56 * 56;         // 3136
static constexpr int NWIN   = BC * 49;         // 401408 windows
static constexpr int NGROUP = NWIN / 4;        // 100352 groups of 4 windows
static constexpr int BLOCKS = 1792;            // 7 blocks/CU exactly
static constexpr int WAVES  = BLOCKS * 4;      // 7168
static constexpr int NITER  = NGROUP / WAVES;  // 14 (exact)

__global__ __launch_bounds__(256) void lrp_pool_kernel(
    const float* __restrict__ x,
    const float* __restrict__ r,
    float* __restrict__ out)
{
    const int tid  = threadIdx.x;
    const int lane = tid & 63;
    const int win  = lane >> 4;   // window within the wave's group of 4
    const int j    = lane & 15;   // lane within the 16-lane window team

    const int g0 = blockIdx.x * 4 + (tid >> 6);

    #pragma unroll 4
    for (int it = 0; it < NITER; ++it) {
        const int g   = g0 + it * WAVES;
        const int wid = g * 4 + win;
        const int bc  = wid / 49;             // magic-mul div
        const int rem = wid - bc * 49;
        const int ohi = rem / 7;
        const int owi = rem - ohi * 7;

        const int row = (ohi << 3) + (j >> 1);
        const int col = (owi << 3) + ((j & 1) << 2);   // float4: cols c..c+3
        const int off = bc * HW + row * 56 + col;      // 16B aligned

        const float4 v  = *reinterpret_cast<const float4*>(x + off);
        const float  rv = r[wid];  // 16 lanes same addr -> broadcast

        // fp64 window sum: per-lane 4-elem sum, then 4-round butterfly
        double s = ((double)v.x + (double)v.y) + ((double)v.z + (double)v.w);
        s += __shfl_xor(s, 1, 64);
        s += __shfl_xor(s, 2, 64);
        s += __shfl_xor(s, 4, 64);
        s += __shfl_xor(s, 8, 64);

        const float denom = (float)(s + 32.0 * 1e-5);
        const float coef  = rv / denom;

        float4 o;
        o.x = v.x * coef;
        o.y = v.y * coef;
        o.z = v.z * coef;
        o.w = v.w * coef;
        *reinterpret_cast<float4*>(out + off) = o;
    }
}

extern "C" void kernel_launch(void* const* d_in, const int* in_sizes, int n_in,
                              void* d_out, int out_size, void* d_ws, size_t ws_size,
                              hipStream_t stream) {
    const float* x   = (const float*)d_in[0];
    const float* r   = (const float*)d_in[1];
    float*       out = (float*)d_out;
    lrp_pool_kernel<<<BLOCKS, 256, 0, stream>>>(x, r, out);
}